// Round 11
// baseline (3450.023 us; speedup 1.0000x reference)
//
#include <hip/hip_runtime.h>
#include <hip/hip_bf16.h>
#include <cstdint>
#include <cstddef>

typedef short v8s __attribute__((ext_vector_type(8)));
typedef float v4f __attribute__((ext_vector_type(4)));
typedef float v16f __attribute__((ext_vector_type(16)));

#define TT 128
#define BB 256
#define HH 1024
#define II 256
#define CC 1000

// short-offsets inside the swizzled-weight region of ws
#define OFF_WHH0 0u
#define OFF_WHH1 1048576u
#define OFF_WIH1 2097152u
#define OFF_WIH0 3145728u
#define WSW_SHORTS 3407872u

#define NJ 32       // 32-col tiles per (layer,group)
#define CSTR 64     // uints per counter line (256 B)
#define CNT_UINTS (12 * CSTR)   // 3 families x 4 groups
#define CNT_BYTES (CNT_UINTS * 4)

#define NCHUNK_LDS 50           // Whh chunks staged in LDS (50 KB)

// scheduling-pipeline pins (no-op if builtin unavailable)
#if defined(__has_builtin)
#if __has_builtin(__builtin_amdgcn_sched_group_barrier)
#define SGB(m, n) __builtin_amdgcn_sched_group_barrier((m), (n), 0)
#endif
#endif
#ifndef SGB
#define SGB(m, n)
#endif
// masks: 0x20 = VMEM read, 0x100 = DS read, 0x8 = MFMA

__device__ __forceinline__ unsigned short f2bf(float f) {
  unsigned int u = __float_as_uint(f);
  u += 0x7fffu + ((u >> 16) & 1u);  // RTNE
  return (unsigned short)(u >> 16);
}
__device__ __forceinline__ float bf2f(unsigned short s) {
  return __uint_as_float((unsigned int)s << 16);
}
__device__ __forceinline__ float fast_tanh(float x) {
  float ax = fabsf(x);
  float e = __expf(-2.0f * ax);
  float r = 1.0f - 2.0f * e / (1.0f + e);
  return x < 0.0f ? -r : r;
}
__device__ __forceinline__ v16f mfma32(v8s a, v8s b, v16f c) {
  return __builtin_amdgcn_mfma_f32_32x32x16_bf16(a, b, c, 0, 0, 0);
}

// Single-address counter poll (all lanes same addr -> one transaction/iter).
__device__ __forceinline__ void poll_cnt(const unsigned int* p, unsigned int need) {
  while (__hip_atomic_load(p, __ATOMIC_RELAXED, __HIP_MEMORY_SCOPE_AGENT) < need)
    __builtin_amdgcn_s_sleep(1);
}
// LDS token spin (zero fabric traffic).
__device__ __forceinline__ void spin_tok(int* tok, int need) {
  while (__hip_atomic_load(tok, __ATOMIC_ACQUIRE, __HIP_MEMORY_SCOPE_WORKGROUP) < need) {}
  asm volatile("" ::: "memory");
}
__device__ __forceinline__ void set_tok(int* tok, int v) {
  __hip_atomic_store(tok, v, __ATOMIC_RELEASE, __HIP_MEMORY_SCOPE_WORKGROUP);
}
// 16B LLC write-through store (input-only constraints — safe).
__device__ __forceinline__ void store16_llc(unsigned short* addr, v8s val) {
  asm volatile("global_store_dwordx4 %0, %1, off sc0 sc1"
               :: "v"(addr), "v"(val) : "memory");
}
__device__ __forceinline__ void waitcnt_vm0() {
  asm volatile("s_waitcnt vmcnt(0)" ::: "memory");
}

// Pre-swizzle W (fp32 [N][K]) into 32x32x16 B-fragment order:
// out[((jt*(K/16)+kk)*64+lane)*8+j] = bf16(W[jt*32+(lane&31)][kk*16+(lane>>5)*8+j])
__global__ void swizzle_w(const float* __restrict__ W, unsigned short* __restrict__ out,
                          int K, int total) {
  int idx = blockIdx.x * 256 + threadIdx.x;
  if (idx >= total) return;
  int lane = idx & 63;
  int rest = idx >> 6;
  int KC = K >> 4;
  int kk = rest & (KC - 1);
  int jt = rest / KC;
  int row = jt * 32 + (lane & 31);
  int k0 = kk * 16 + (lane >> 5) * 8;
  const float* src = W + (size_t)row * K + k0;
  float4 f0 = *(const float4*)src;
  float4 f1 = *(const float4*)(src + 4);
  unsigned short o[8] = {f2bf(f0.x), f2bf(f0.y), f2bf(f0.z), f2bf(f0.w),
                         f2bf(f1.x), f2bf(f1.y), f2bf(f1.z), f2bf(f1.w)};
  *(v8s*)(out + (size_t)idx * 8) = *(const v8s*)o;
}

// xp = bias + x @ Wih0^T, bf16, consumer D-fragment layout (proven r6-r10):
// xp[(((t*4+g)*32+jt)*2+tile)*1024 + lane*16 + r]
__global__ __launch_bounds__(256, 1) void xp_kernel(
    const float* __restrict__ x, const unsigned short* __restrict__ wih_sw,
    const float* __restrict__ bih0, const float* __restrict__ bhh0,
    unsigned short* __restrict__ xp) {
  __shared__ unsigned short lA[16 * 64 * 8];
  const int tid = threadIdx.x;
  const int lane = tid & 63, wave = tid >> 6;
  const int bi = blockIdx.x;           // 1024 blocks: (t*4+g)*2+tile
  const int t = bi >> 3, g = (bi >> 1) & 3, tile = bi & 1;
  const int b0 = g * 64 + tile * 32;
  #pragma unroll
  for (int s = 0; s < 4; ++s) {
    int idx = s * 256 + tid;
    int row = idx >> 5, kg = idx & 31;
    const float* src = x + ((size_t)(b0 + row) * TT + t) * II + kg * 8;
    float4 f0 = *(const float4*)src;
    float4 f1 = *(const float4*)(src + 4);
    unsigned short o[8] = {f2bf(f0.x), f2bf(f0.y), f2bf(f0.z), f2bf(f0.w),
                           f2bf(f1.x), f2bf(f1.y), f2bf(f1.z), f2bf(f1.w)};
    int kk = kg >> 1, hf = kg & 1;
    *(v8s*)(lA + ((size_t)kk * 64 + hf * 32 + row) * 8) = *(const v8s*)o;
  }
  __syncthreads();
  const int col = lane & 31;
  for (int jj = 0; jj < 8; ++jj) {
    int jt = wave * 8 + jj;
    float bias = bih0[jt * 32 + col] + bhh0[jt * 32 + col];
    v16f acc;
    #pragma unroll
    for (int r = 0; r < 16; ++r) acc[r] = bias;
    const unsigned short* bw = wih_sw + (size_t)jt * 8192;
    #pragma unroll 4
    for (int kk = 0; kk < 16; ++kk) {
      v8s a = *(const v8s*)(lA + ((size_t)kk * 64 + lane) * 8);
      v8s b = *(const v8s*)(bw + ((size_t)kk * 64 + lane) * 8);
      acc = mfma32(a, b, acc);
    }
    unsigned short o[16];
    #pragma unroll
    for (int r = 0; r < 16; ++r) o[r] = f2bf(acc[r]);
    unsigned short* dst = xp + ((size_t)((t * 4 + g) * 32 + jt) * 2 + tile) * 1024 + lane * 16;
    *(v8s*)dst = *(const v8s*)o;
    *(v8s*)(dst + 8) = *(const v8s*)(o + 8);
  }
}

// Fused 2-layer RNN. Grid 256 blocks (1/CU), 256 threads (4 waves).
// Round-8/10 proven structure. NEW: sched_group_barrier-pinned load pipelines
// (all VMEM reads of a site issue before any MFMA -> true depth 32-64) and
// per-wave sub-signals (counter target 128*t; vmcnt is per-wave).
template <int XPON, int BIGH2>
__global__ __launch_bounds__(256, 1) void rnn_fused(
    const float* __restrict__ x, const unsigned short* __restrict__ wsw,
    const unsigned short* __restrict__ xp,
    const float* __restrict__ bih0, const float* __restrict__ bhh0,
    const float* __restrict__ bih1, const float* __restrict__ bhh1,
    unsigned short* __restrict__ hbuf, unsigned short* __restrict__ h2buf,
    unsigned int* cnt) {
  __shared__ unsigned short lds_whh[NCHUNK_LDS * 512];  // 50 KB
  __shared__ float lds_acc[2 * 1024];                   // 8 KB
  __shared__ unsigned short lds_pack[64 * 40];          // 5 KB
  __shared__ int tok[4];                                // A, X, B tokens

  const int tid = threadIdx.x;
  const int xsel = blockIdx.x & 7;
  const int layer = xsel >> 2;
  const int g = xsel & 3;
  const int jt = blockIdx.x >> 3;
  const int lane = tid & 63;
  const int wave = tid >> 6;
  const int tile = wave & 1;
  const int kh = wave >> 1;
  const int col = lane & 31;
  const int half = lane >> 5;
  const int j0 = jt * 32;

  const unsigned short* whh_tile =
      wsw + (layer ? OFF_WHH1 : OFF_WHH0) + (size_t)jt * 32768;
  const unsigned short* wih_tile =
      layer ? (wsw + OFF_WIH1 + (size_t)jt * 32768)
            : (wsw + OFF_WIH0 + (size_t)jt * 8192);

  for (int i = tid * 8; i < NCHUNK_LDS * 512; i += 2048)
    *(v8s*)(lds_whh + i) = *(const v8s*)(whh_tile + i);

  float bias = 0.0f;
  if (layer == 1) bias = bih1[j0 + col] + bhh1[j0 + col];
  else if (!XPON) bias = bih0[j0 + col] + bhh0[j0 + col];
  if (tid < 4) tok[tid] = 0;
  __syncthreads();

  const int arow = g * 64 + tile * 32 + col;
  unsigned int* cntA_g = cnt + (size_t)(0 * 4 + g) * CSTR;
  unsigned int* cntX_g = cnt + (size_t)(1 * 4 + g) * CSTR;
  unsigned int* cntB_g = cnt + (size_t)(2 * 4 + g) * CSTR;

  // xp prefetch (layer0 kh0 waves)
  v8s xc0 = {}, xc1 = {};
  const unsigned short* xpb =
      xp + (((size_t)g * 32 + jt) * 2 + tile) * 1024 + lane * 16;
  if (XPON && layer == 0 && kh == 0) {
    xc0 = *(const v8s*)xpb;
    xc1 = *(const v8s*)(xpb + 8);
  }

  // B-fragment helpers
  auto bL = [&](int kk) -> v8s {
    return *(const v8s*)(lds_whh + ((size_t)kk * 64 + lane) * 8);
  };
  auto bG = [&](int kk) -> v8s {
    return *(const v8s*)(whh_tile + ((size_t)kk * 64 + lane) * 8);
  };
  auto bI = [&](int kk) -> v8s {
    return *(const v8s*)(wih_tile + ((size_t)kk * 64 + lane) * 8);
  };

  for (int t = 0; t < TT; ++t) {
    v16f acc = {};

    if (layer == 0) {
      if (kh == 0) {
        if (XPON) {
          union { v8s v[2]; unsigned short u[16]; } xu;
          xu.v[0] = xc0; xu.v[1] = xc1;
          #pragma unroll
          for (int r = 0; r < 16; ++r) acc[r] = bf2f(xu.u[r]);
          // prefetch next step's xp NOW — in flight across the gate wait
          int tn = (t + 1 < TT) ? (t + 1) : (TT - 1);
          const unsigned short* nx = xpb + (size_t)tn * 262144;
          xc0 = *(const v8s*)nx;
          xc1 = *(const v8s*)(nx + 8);
        } else {
          #pragma unroll
          for (int r = 0; r < 16; ++r) acc[r] = bias;
          const float* xr = x + ((size_t)arow * TT + t) * II + half * 8;
          #pragma unroll 4
          for (int kk = 0; kk < 16; ++kk) {
            float4 f0 = *(const float4*)(xr + kk * 16);
            float4 f1 = *(const float4*)(xr + kk * 16 + 4);
            unsigned short o[8] = {f2bf(f0.x), f2bf(f0.y), f2bf(f0.z), f2bf(f0.w),
                                   f2bf(f1.x), f2bf(f1.y), f2bf(f1.z), f2bf(f1.w)};
            acc = mfma32(*(const v8s*)o, bI(kk), acc);
          }
        }
        if (t > 0) {
          if (wave == 0) { poll_cnt(cntA_g, 128u * (unsigned)t); set_tok(&tok[0], t); }
          else           { spin_tok(&tok[0], t); }
          const unsigned short* hr = hbuf + ((size_t)t * BB + arow) * HH + half * 8;
          v8s ar[32];
          #pragma unroll
          for (int kk = 0; kk < 32; ++kk) ar[kk] = *(const v8s*)(hr + kk * 16);
          #pragma unroll
          for (int kk = 0; kk < 32; ++kk) acc = mfma32(ar[kk], bL(kk), acc);
          SGB(0x20, 32);    // all 32 h-loads first
          SGB(0x108, 64);   // then ds_reads + MFMAs
        }
      } else {
        if (t > 0) {
          spin_tok(&tok[0], t);
          const unsigned short* hr = hbuf + ((size_t)t * BB + arow) * HH + half * 8;
          v8s ar[32];
          #pragma unroll
          for (int kk = 0; kk < 32; ++kk) ar[kk] = *(const v8s*)(hr + (32 + kk) * 16);
          #pragma unroll
          for (int kk = 0; kk < 32; ++kk) {
            v8s b = (32 + kk < NCHUNK_LDS) ? bL(32 + kk) : bG(32 + kk);
            acc = mfma32(ar[kk], b, acc);
          }
          SGB(0x20, 46);    // 32 h-loads + 14 global-B loads
          SGB(0x108, 50);   // 18 ds_reads + 32 MFMAs
        }
      }
    } else {
      if (kh == 0) {
        #pragma unroll
        for (int r = 0; r < 16; ++r) acc[r] = bias;
        if (wave == 0) { poll_cnt(cntX_g, 128u * (unsigned)(t + 1)); set_tok(&tok[1], t + 1); }
        else           { spin_tok(&tok[1], t + 1); }
        const unsigned short* hr = hbuf + ((size_t)(t + 1) * BB + arow) * HH + half * 8;
        v8s ar[32];
        #pragma unroll
        for (int kk = 0; kk < 32; ++kk) ar[kk] = *(const v8s*)(hr + kk * 16);
        #pragma unroll
        for (int kk = 0; kk < 32; ++kk) acc = mfma32(ar[kk], bI(kk), acc);
        SGB(0x20, 64);    // 32 h-loads + 32 wih-loads
        SGB(0x8, 32);
        #pragma unroll
        for (int kk = 0; kk < 32; ++kk) ar[kk] = *(const v8s*)(hr + (32 + kk) * 16);
        #pragma unroll
        for (int kk = 0; kk < 32; ++kk) acc = mfma32(ar[kk], bI(32 + kk), acc);
        SGB(0x20, 64);
        SGB(0x8, 32);
      } else {
        if (t > 0) {
          if (wave == 2) { poll_cnt(cntB_g, 128u * (unsigned)t); set_tok(&tok[2], t); }
          else           { spin_tok(&tok[2], t); }
          const int slot_r = BIGH2 ? (t - 1) : ((t - 1) & 1);
          const unsigned short* hr =
              h2buf + ((size_t)slot_r * BB + arow) * HH + half * 8;
          if (BIGH2) {
            v8s ar[32];
            #pragma unroll
            for (int kk = 0; kk < 32; ++kk) ar[kk] = *(const v8s*)(hr + kk * 16);
            #pragma unroll
            for (int kk = 0; kk < 32; ++kk) acc = mfma32(ar[kk], bL(kk), acc);
            SGB(0x20, 32);
            SGB(0x108, 64);
            #pragma unroll
            for (int kk = 0; kk < 32; ++kk) ar[kk] = *(const v8s*)(hr + (32 + kk) * 16);
            #pragma unroll
            for (int kk = 0; kk < 32; ++kk) {
              v8s b = (32 + kk < NCHUNK_LDS) ? bL(32 + kk) : bG(32 + kk);
              acc = mfma32(ar[kk], b, acc);
            }
            SGB(0x20, 46);
            SGB(0x108, 50);
          } else {
            #pragma unroll 8
            for (int kk = 0; kk < 64; ++kk) {
              const unsigned long long* p = (const unsigned long long*)(hr + kk * 16);
              unsigned long long lo = __hip_atomic_load(p, __ATOMIC_RELAXED, __HIP_MEMORY_SCOPE_AGENT);
              unsigned long long hi = __hip_atomic_load(p + 1, __ATOMIC_RELAXED, __HIP_MEMORY_SCOPE_AGENT);
              union { unsigned long long q[2]; v8s v; } u;
              u.q[0] = lo; u.q[1] = hi;
              v8s b = (kk < NCHUNK_LDS) ? bL(kk) : bG(kk);
              acc = mfma32(u.v, b, acc);
            }
          }
        }
      }
    }

    // ---- cross-wave K reduction (16B lane stride, conflict-free) ----
    if (kh == 1) {
      float* dst = lds_acc + tile * 1024;
      #pragma unroll
      for (int r4 = 0; r4 < 4; ++r4)
        *(float4*)(dst + r4 * 256 + lane * 4) =
            make_float4(acc[r4 * 4], acc[r4 * 4 + 1], acc[r4 * 4 + 2], acc[r4 * 4 + 3]);
    }
    __syncthreads();

    // ---- sum + tanh + transpose to LDS (row-major bf16, stride 40) ----
    if (kh == 0) {
      const float* srcp = lds_acc + tile * 1024;
      #pragma unroll
      for (int r4 = 0; r4 < 4; ++r4) {
        float4 part = *(const float4*)(srcp + r4 * 256 + lane * 4);
        float pv[4] = {part.x, part.y, part.z, part.w};
        #pragma unroll
        for (int q = 0; q < 4; ++q) {
          int r = r4 * 4 + q;
          int row_l = tile * 32 + q + 8 * r4 + 4 * half;
          lds_pack[row_l * 40 + col] = f2bf(fast_tanh(acc[r] + pv[q]));
        }
      }
    }
    __syncthreads();

    // ---- packed h store + per-wave sub-signal (vmcnt is per-wave) ----
    {
      int row_l = tid >> 2, cg = tid & 3;
      v8s hv = *(const v8s*)(lds_pack + row_l * 40 + cg * 8);
      int slot_w = layer ? (BIGH2 ? t : (t & 1)) : (t + 1);
      unsigned short* hout = (layer ? h2buf : hbuf) +
          ((size_t)slot_w * BB + g * 64 + row_l) * HH + j0 + cg * 8;
      store16_llc(hout, hv);
    }
    waitcnt_vm0();       // this wave's stores drained to LLC
    if (lane == 0) {
      if (layer == 0) {
        __hip_atomic_fetch_add(cntA_g, 1u, __ATOMIC_RELAXED, __HIP_MEMORY_SCOPE_AGENT);
        __hip_atomic_fetch_add(cntX_g, 1u, __ATOMIC_RELAXED, __HIP_MEMORY_SCOPE_AGENT);
      } else {
        __hip_atomic_fetch_add(cntB_g, 1u, __ATOMIC_RELAXED, __HIP_MEMORY_SCOPE_AGENT);
      }
    }
    __syncthreads();     // protects lds_acc/lds_pack reuse next step
  }
}

// out[b][c] = h2_last[b][:] . fcW[c][:] + fcb[c]
__global__ __launch_bounds__(256, 1) void fc_kernel(
    const unsigned short* __restrict__ h2, const float* __restrict__ fcW,
    const float* __restrict__ fcb, float* __restrict__ out) {
  const int tid = threadIdx.x;
  const int ct = blockIdx.x % 63;
  const int g = blockIdx.x / 63;
  const int lane = tid & 63;
  const int wave = tid >> 6;
  const int n = lane & 15;
  const int quad = lane >> 4;
  const int c = ct * 16 + n;
  const int cs = c < CC ? c : CC - 1;
  const float bias = fcb[cs];
  v4f acc = {bias, bias, bias, bias};
  const unsigned short* hr = h2 + (size_t)(g * 64 + wave * 16 + n) * HH + quad * 8;
  const float* wr = fcW + (size_t)cs * HH + quad * 8;
  #pragma unroll 8
  for (int kk = 0; kk < HH / 32; ++kk) {
    v8s a = *(const v8s*)(hr + kk * 32);
    float4 f0 = *(const float4*)(wr + kk * 32);
    float4 f1 = *(const float4*)(wr + kk * 32 + 4);
    v8s b;
    b[0] = (short)f2bf(f0.x); b[1] = (short)f2bf(f0.y);
    b[2] = (short)f2bf(f0.z); b[3] = (short)f2bf(f0.w);
    b[4] = (short)f2bf(f1.x); b[5] = (short)f2bf(f1.y);
    b[6] = (short)f2bf(f1.z); b[7] = (short)f2bf(f1.w);
    acc = __builtin_amdgcn_mfma_f32_16x16x32_bf16(a, b, acc, 0, 0, 0);
  }
  if (c < CC) {
    const int b0 = g * 64 + wave * 16 + quad * 4;
    #pragma unroll
    for (int i = 0; i < 4; ++i) out[(size_t)(b0 + i) * CC + c] = acc[i];
  }
}

extern "C" void kernel_launch(void* const* d_in, const int* in_sizes, int n_in,
                              void* d_out, int out_size, void* d_ws, size_t ws_size,
                              hipStream_t stream) {
  (void)in_sizes; (void)n_in; (void)out_size;
  const float* x    = (const float*)d_in[0];
  const float* Wih0 = (const float*)d_in[1];
  const float* Whh0 = (const float*)d_in[2];
  const float* bih0 = (const float*)d_in[3];
  const float* bhh0 = (const float*)d_in[4];
  const float* Wih1 = (const float*)d_in[5];
  const float* Whh1 = (const float*)d_in[6];
  const float* bih1 = (const float*)d_in[7];
  const float* bhh1 = (const float*)d_in[8];
  const float* fcW  = (const float*)d_in[9];
  const float* fcb  = (const float*)d_in[10];

  const size_t hbuf_elems = (size_t)(TT + 1) * BB * HH;   // 129 slots
  const size_t h2_full = (size_t)TT * BB * HH;
  const size_t h2_par  = (size_t)2 * BB * HH;
  const size_t xp_elems = (size_t)TT * BB * HH;

  const size_t needA = (WSW_SHORTS + hbuf_elems + h2_full + xp_elems) * 2 + CNT_BYTES;
  const size_t needB = (WSW_SHORTS + hbuf_elems + h2_par + xp_elems) * 2 + CNT_BYTES;
  const bool tierA = ws_size >= needA;
  const bool tierB = !tierA && ws_size >= needB;

  unsigned short* wsw = (unsigned short*)d_ws;
  unsigned short* hbuf = wsw + WSW_SHORTS;
  unsigned short* h2buf = hbuf + hbuf_elems;
  unsigned short* xpbuf = h2buf + (tierA ? h2_full : h2_par);
  unsigned int* cnt = (unsigned int*)(xpbuf + ((tierA || tierB) ? xp_elems : 0));

  hipMemsetAsync(cnt, 0, CNT_BYTES, stream);
  swizzle_w<<<512, 256, 0, stream>>>(Whh0, wsw + OFF_WHH0, HH, 32 * 64 * 64);
  swizzle_w<<<512, 256, 0, stream>>>(Whh1, wsw + OFF_WHH1, HH, 32 * 64 * 64);
  swizzle_w<<<512, 256, 0, stream>>>(Wih1, wsw + OFF_WIH1, HH, 32 * 64 * 64);
  swizzle_w<<<128, 256, 0, stream>>>(Wih0, wsw + OFF_WIH0, II, 32 * 16 * 64);

  if (tierA || tierB)
    xp_kernel<<<1024, 256, 0, stream>>>(x, wsw + OFF_WIH0, bih0, bhh0, xpbuf);

  if (tierA) {
    rnn_fused<1, 1><<<256, 256, 0, stream>>>(
        x, wsw, xpbuf, bih0, bhh0, bih1, bhh1, hbuf, h2buf, cnt);
  } else if (tierB) {
    rnn_fused<1, 0><<<256, 256, 0, stream>>>(
        x, wsw, xpbuf, bih0, bhh0, bih1, bhh1, hbuf, h2buf, cnt);
  } else {
    rnn_fused<0, 0><<<256, 256, 0, stream>>>(
        x, wsw, xpbuf, bih0, bhh0, bih1, bhh1, hbuf, h2buf, cnt);
  }

  const unsigned short* h2last = h2buf + (size_t)(tierA ? (TT - 1) : 1) * BB * HH;
  fc_kernel<<<63 * 4, 256, 0, stream>>>(h2last, fcW, fcb, (float*)d_out);
}

// Round 12
// 1398.758 us; speedup vs baseline: 2.4665x; 2.4665x over previous
//
#include <hip/hip_runtime.h>
#include <hip/hip_bf16.h>
#include <cstdint>
#include <cstddef>

typedef short v8s __attribute__((ext_vector_type(8)));
typedef float v4f __attribute__((ext_vector_type(4)));
typedef float v16f __attribute__((ext_vector_type(16)));

#define TT 128
#define BB 256
#define HH 1024
#define II 256
#define CC 1000

#define OFF_WHH0 0u
#define OFF_WHH1 1048576u
#define OFF_WIH1 2097152u
#define OFF_WIH0 3145728u
#define WSW_SHORTS 3407872u

#define NJ 32
#define CSTR 64
#define CNT_UINTS (12 * CSTR)
#define CNT_BYTES (CNT_UINTS * 4)

#define NCHUNK_LDS 50

__device__ __forceinline__ unsigned short f2bf(float f) {
  unsigned int u = __float_as_uint(f);
  u += 0x7fffu + ((u >> 16) & 1u);  // RTNE
  return (unsigned short)(u >> 16);
}
__device__ __forceinline__ float bf2f(unsigned short s) {
  return __uint_as_float((unsigned int)s << 16);
}
__device__ __forceinline__ float fast_tanh(float x) {
  float ax = fabsf(x);
  float e = __expf(-2.0f * ax);
  float r = 1.0f - 2.0f * e / (1.0f + e);
  return x < 0.0f ? -r : r;
}
__device__ __forceinline__ v16f mfma32(v8s a, v8s b, v16f c) {
  return __builtin_amdgcn_mfma_f32_32x32x16_bf16(a, b, c, 0, 0, 0);
}

// h exchange in MFMA-A-fragment order: hfrag[slot][g][tile][kk<64][lane<64][8]
// element (row,k): tile=(row>>5)&1, kk=k>>4, lane=(row&31)+32*((k>>3)&1), j=k&7
__device__ __forceinline__ size_t frag_off(int slot, int g, int tile) {
  return ((((size_t)slot * 4 + g) * 2 + tile) << 15);   // *32768 shorts (64 KB)
}

__device__ __forceinline__ void poll_cnt(const unsigned int* p, unsigned int need) {
  while (__hip_atomic_load(p, __ATOMIC_RELAXED, __HIP_MEMORY_SCOPE_AGENT) < need)
    __builtin_amdgcn_s_sleep(1);
}
__device__ __forceinline__ void spin_tok(int* tok, int need) {
  while (__hip_atomic_load(tok, __ATOMIC_ACQUIRE, __HIP_MEMORY_SCOPE_WORKGROUP) < need) {}
  asm volatile("" ::: "memory");
}
__device__ __forceinline__ void set_tok(int* tok, int v) {
  __hip_atomic_store(tok, v, __ATOMIC_RELEASE, __HIP_MEMORY_SCOPE_WORKGROUP);
}
__device__ __forceinline__ void store16_llc(unsigned short* addr, v8s val) {
  asm volatile("global_store_dwordx4 %0, %1, off sc0 sc1"
               :: "v"(addr), "v"(val) : "memory");
}
__device__ __forceinline__ void waitcnt_vm0() {
  asm volatile("s_waitcnt vmcnt(0)" ::: "memory");
}

__global__ void swizzle_w(const float* __restrict__ W, unsigned short* __restrict__ out,
                          int K, int total) {
  int idx = blockIdx.x * 256 + threadIdx.x;
  if (idx >= total) return;
  int lane = idx & 63;
  int rest = idx >> 6;
  int KC = K >> 4;
  int kk = rest & (KC - 1);
  int jt = rest / KC;
  int row = jt * 32 + (lane & 31);
  int k0 = kk * 16 + (lane >> 5) * 8;
  const float* src = W + (size_t)row * K + k0;
  float4 f0 = *(const float4*)src;
  float4 f1 = *(const float4*)(src + 4);
  unsigned short o[8] = {f2bf(f0.x), f2bf(f0.y), f2bf(f0.z), f2bf(f0.w),
                         f2bf(f1.x), f2bf(f1.y), f2bf(f1.z), f2bf(f1.w)};
  *(v8s*)(out + (size_t)idx * 8) = *(const v8s*)o;
}

// xp = bias + x @ Wih0^T, bf16, consumer D-fragment layout (proven r6-r10)
__global__ __launch_bounds__(256, 1) void xp_kernel(
    const float* __restrict__ x, const unsigned short* __restrict__ wih_sw,
    const float* __restrict__ bih0, const float* __restrict__ bhh0,
    unsigned short* __restrict__ xp) {
  __shared__ unsigned short lA[16 * 64 * 8];
  const int tid = threadIdx.x;
  const int lane = tid & 63, wave = tid >> 6;
  const int bi = blockIdx.x;
  const int t = bi >> 3, g = (bi >> 1) & 3, tile = bi & 1;
  const int b0 = g * 64 + tile * 32;
  #pragma unroll
  for (int s = 0; s < 4; ++s) {
    int idx = s * 256 + tid;
    int row = idx >> 5, kg = idx & 31;
    const float* src = x + ((size_t)(b0 + row) * TT + t) * II + kg * 8;
    float4 f0 = *(const float4*)src;
    float4 f1 = *(const float4*)(src + 4);
    unsigned short o[8] = {f2bf(f0.x), f2bf(f0.y), f2bf(f0.z), f2bf(f0.w),
                           f2bf(f1.x), f2bf(f1.y), f2bf(f1.z), f2bf(f1.w)};
    int kk = kg >> 1, hf = kg & 1;
    *(v8s*)(lA + ((size_t)kk * 64 + hf * 32 + row) * 8) = *(const v8s*)o;
  }
  __syncthreads();
  const int col = lane & 31;
  for (int jj = 0; jj < 8; ++jj) {
    int jt = wave * 8 + jj;
    float bias = bih0[jt * 32 + col] + bhh0[jt * 32 + col];
    v16f acc;
    #pragma unroll
    for (int r = 0; r < 16; ++r) acc[r] = bias;
    const unsigned short* bw = wih_sw + (size_t)jt * 8192;
    #pragma unroll 4
    for (int kk = 0; kk < 16; ++kk) {
      v8s a = *(const v8s*)(lA + ((size_t)kk * 64 + lane) * 8);
      v8s b = *(const v8s*)(bw + ((size_t)kk * 64 + lane) * 8);
      acc = mfma32(a, b, acc);
    }
    unsigned short o[16];
    #pragma unroll
    for (int r = 0; r < 16; ++r) o[r] = f2bf(acc[r]);
    unsigned short* dst = xp + ((size_t)((t * 4 + g) * 32 + jt) * 2 + tile) * 1024 + lane * 16;
    *(v8s*)dst = *(const v8s*)o;
    *(v8s*)(dst + 8) = *(const v8s*)(o + 8);
  }
}

// Fused 2-layer RNN: round-10 structure + A-fragment h exchange (dense reads,
// identical addresses across the 32 consumer blocks of a group -> L2-shared).
template <int XPON, int BIGH2>
__global__ __launch_bounds__(256, 1) void rnn_fused(
    const float* __restrict__ x, const unsigned short* __restrict__ wsw,
    const unsigned short* __restrict__ xp,
    const float* __restrict__ bih0, const float* __restrict__ bhh0,
    const float* __restrict__ bih1, const float* __restrict__ bhh1,
    unsigned short* __restrict__ hbuf, unsigned short* __restrict__ h2buf,
    unsigned int* cnt) {
  __shared__ unsigned short lds_whh[NCHUNK_LDS * 512];
  __shared__ float lds_acc[2 * 1024];
  __shared__ unsigned short lds_pack[64 * 40];
  __shared__ int tok[4];

  const int tid = threadIdx.x;
  const int xsel = blockIdx.x & 7;
  const int layer = xsel >> 2;
  const int g = xsel & 3;
  const int jt = blockIdx.x >> 3;
  const int lane = tid & 63;
  const int wave = tid >> 6;
  const int tile = wave & 1;
  const int kh = wave >> 1;
  const int col = lane & 31;
  const int half = lane >> 5;
  const int j0 = jt * 32;

  const unsigned short* whh_tile =
      wsw + (layer ? OFF_WHH1 : OFF_WHH0) + (size_t)jt * 32768;
  const unsigned short* wih_tile =
      layer ? (wsw + OFF_WIH1 + (size_t)jt * 32768)
            : (wsw + OFF_WIH0 + (size_t)jt * 8192);

  for (int i = tid * 8; i < NCHUNK_LDS * 512; i += 2048)
    *(v8s*)(lds_whh + i) = *(const v8s*)(whh_tile + i);

  float bias = 0.0f;
  if (layer == 1) bias = bih1[j0 + col] + bhh1[j0 + col];
  else if (!XPON) bias = bih0[j0 + col] + bhh0[j0 + col];
  if (tid < 4) tok[tid] = 0;
  __syncthreads();

  const int arow = g * 64 + tile * 32 + col;
  unsigned int* cntA_g = cnt + (size_t)(0 * 4 + g) * CSTR;
  unsigned int* cntX_g = cnt + (size_t)(1 * 4 + g) * CSTR;
  unsigned int* cntB_g = cnt + (size_t)(2 * 4 + g) * CSTR;

  v8s xc0 = {}, xc1 = {};
  const unsigned short* xpb =
      xp + (((size_t)g * 32 + jt) * 2 + tile) * 1024 + lane * 16;
  if (XPON && layer == 0 && kh == 0) {
    xc0 = *(const v8s*)xpb;
    xc1 = *(const v8s*)(xpb + 8);
  }

  auto bL = [&](int kk) -> v8s {
    return *(const v8s*)(lds_whh + ((size_t)kk * 64 + lane) * 8);
  };
  auto bG = [&](int kk) -> v8s {
    return *(const v8s*)(whh_tile + ((size_t)kk * 64 + lane) * 8);
  };
  auto bI = [&](int kk) -> v8s {
    return *(const v8s*)(wih_tile + ((size_t)kk * 64 + lane) * 8);
  };

  for (int t = 0; t < TT; ++t) {
    v16f acc = {};

    if (layer == 0) {
      if (kh == 0) {
        if (XPON) {
          union { v8s v[2]; unsigned short u[16]; } xu;
          xu.v[0] = xc0; xu.v[1] = xc1;
          #pragma unroll
          for (int r = 0; r < 16; ++r) acc[r] = bf2f(xu.u[r]);
        } else {
          #pragma unroll
          for (int r = 0; r < 16; ++r) acc[r] = bias;
          const float* xr = x + ((size_t)arow * TT + t) * II + half * 8;
          #pragma unroll 4
          for (int kk = 0; kk < 16; ++kk) {
            float4 f0 = *(const float4*)(xr + kk * 16);
            float4 f1 = *(const float4*)(xr + kk * 16 + 4);
            unsigned short o[8] = {f2bf(f0.x), f2bf(f0.y), f2bf(f0.z), f2bf(f0.w),
                                   f2bf(f1.x), f2bf(f1.y), f2bf(f1.z), f2bf(f1.w)};
            acc = mfma32(*(const v8s*)o, bI(kk), acc);
          }
        }
        if (t > 0) {
          if (wave == 0) { poll_cnt(cntA_g, 32u * (unsigned)t); set_tok(&tok[0], t); }
          else           { spin_tok(&tok[0], t); }
          const unsigned short* hr = hbuf + frag_off(t, g, tile) + (size_t)lane * 8;
          v8s aA[16], aB[16];
          #pragma unroll
          for (int kk = 0; kk < 16; ++kk) aA[kk] = *(const v8s*)(hr + kk * 512);
          #pragma unroll
          for (int kk = 0; kk < 16; ++kk) aB[kk] = *(const v8s*)(hr + (16 + kk) * 512);
          #pragma unroll
          for (int kk = 0; kk < 16; ++kk) acc = mfma32(aA[kk], bL(kk), acc);
          #pragma unroll
          for (int kk = 0; kk < 16; ++kk) acc = mfma32(aB[kk], bL(16 + kk), acc);
        }
        if (XPON) {
          int tn = (t + 1 < TT) ? (t + 1) : (TT - 1);
          const unsigned short* nx = xpb + (size_t)tn * 262144;
          xc0 = *(const v8s*)nx;
          xc1 = *(const v8s*)(nx + 8);
        }
      } else {
        if (t > 0) {
          spin_tok(&tok[0], t);
          const unsigned short* hr = hbuf + frag_off(t, g, tile) + (size_t)lane * 8;
          v8s aA[16], aB[16];
          #pragma unroll
          for (int kk = 0; kk < 16; ++kk) aA[kk] = *(const v8s*)(hr + (32 + kk) * 512);
          #pragma unroll
          for (int kk = 0; kk < 16; ++kk) aB[kk] = *(const v8s*)(hr + (48 + kk) * 512);
          #pragma unroll
          for (int kk = 0; kk < 16; ++kk) {
            v8s b = (32 + kk < NCHUNK_LDS) ? bL(32 + kk) : bG(32 + kk);
            acc = mfma32(aA[kk], b, acc);
          }
          #pragma unroll
          for (int kk = 0; kk < 16; ++kk) {
            v8s b = (48 + kk < NCHUNK_LDS) ? bL(48 + kk) : bG(48 + kk);
            acc = mfma32(aB[kk], b, acc);
          }
        }
      }
    } else {
      if (kh == 0) {
        #pragma unroll
        for (int r = 0; r < 16; ++r) acc[r] = bias;
        if (wave == 0) { poll_cnt(cntX_g, 32u * (unsigned)(t + 1)); set_tok(&tok[1], t + 1); }
        else           { spin_tok(&tok[1], t + 1); }
        const unsigned short* hr = hbuf + frag_off(t + 1, g, tile) + (size_t)lane * 8;
        v8s aA[16], aB[16];
        #pragma unroll
        for (int kk = 0; kk < 16; ++kk) aA[kk] = *(const v8s*)(hr + kk * 512);
        #pragma unroll
        for (int kk = 0; kk < 16; ++kk) aB[kk] = *(const v8s*)(hr + (16 + kk) * 512);
        #pragma unroll
        for (int kk = 0; kk < 16; ++kk) acc = mfma32(aA[kk], bI(kk), acc);
        #pragma unroll
        for (int kk = 0; kk < 16; ++kk) aA[kk] = *(const v8s*)(hr + (32 + kk) * 512);
        #pragma unroll
        for (int kk = 0; kk < 16; ++kk) acc = mfma32(aB[kk], bI(16 + kk), acc);
        #pragma unroll
        for (int kk = 0; kk < 16; ++kk) aB[kk] = *(const v8s*)(hr + (48 + kk) * 512);
        #pragma unroll
        for (int kk = 0; kk < 16; ++kk) acc = mfma32(aA[kk], bI(32 + kk), acc);
        #pragma unroll
        for (int kk = 0; kk < 16; ++kk) acc = mfma32(aB[kk], bI(48 + kk), acc);
      } else {
        if (t > 0) {
          if (wave == 2) { poll_cnt(cntB_g, 32u * (unsigned)t); set_tok(&tok[2], t); }
          else           { spin_tok(&tok[2], t); }
          const int slot_r = BIGH2 ? (t - 1) : ((t - 1) & 1);
          const unsigned short* hr = h2buf + frag_off(slot_r, g, tile) + (size_t)lane * 8;
          if (BIGH2) {
            v8s aA[16], aB[16];
            #pragma unroll
            for (int kk = 0; kk < 16; ++kk) aA[kk] = *(const v8s*)(hr + kk * 512);
            #pragma unroll
            for (int kk = 0; kk < 16; ++kk) aB[kk] = *(const v8s*)(hr + (16 + kk) * 512);
            #pragma unroll
            for (int kk = 0; kk < 16; ++kk) acc = mfma32(aA[kk], bL(kk), acc);
            #pragma unroll
            for (int kk = 0; kk < 16; ++kk) aA[kk] = *(const v8s*)(hr + (32 + kk) * 512);
            #pragma unroll
            for (int kk = 0; kk < 16; ++kk) acc = mfma32(aB[kk], bL(16 + kk), acc);
            #pragma unroll
            for (int kk = 0; kk < 16; ++kk) aB[kk] = *(const v8s*)(hr + (48 + kk) * 512);
            #pragma unroll
            for (int kk = 0; kk < 16; ++kk) {
              v8s b = (32 + kk < NCHUNK_LDS) ? bL(32 + kk) : bG(32 + kk);
              acc = mfma32(aA[kk], b, acc);
            }
            #pragma unroll
            for (int kk = 0; kk < 16; ++kk) {
              v8s b = (48 + kk < NCHUNK_LDS) ? bL(48 + kk) : bG(48 + kk);
              acc = mfma32(aB[kk], b, acc);
            }
          } else {
            #pragma unroll 8
            for (int kk = 0; kk < 64; ++kk) {
              const unsigned long long* p = (const unsigned long long*)(hr + kk * 512);
              unsigned long long lo = __hip_atomic_load(p, __ATOMIC_RELAXED, __HIP_MEMORY_SCOPE_AGENT);
              unsigned long long hi = __hip_atomic_load(p + 1, __ATOMIC_RELAXED, __HIP_MEMORY_SCOPE_AGENT);
              union { unsigned long long q[2]; v8s v; } u;
              u.q[0] = lo; u.q[1] = hi;
              v8s b = (kk < NCHUNK_LDS) ? bL(kk) : bG(kk);
              acc = mfma32(u.v, b, acc);
            }
          }
        }
      }
    }

    if (kh == 1) {
      float* dst = lds_acc + tile * 1024;
      #pragma unroll
      for (int r4 = 0; r4 < 4; ++r4)
        *(float4*)(dst + r4 * 256 + lane * 4) =
            make_float4(acc[r4 * 4], acc[r4 * 4 + 1], acc[r4 * 4 + 2], acc[r4 * 4 + 3]);
    }
    __syncthreads();

    if (kh == 0) {
      const float* srcp = lds_acc + tile * 1024;
      #pragma unroll
      for (int r4 = 0; r4 < 4; ++r4) {
        float4 part = *(const float4*)(srcp + r4 * 256 + lane * 4);
        float pv[4] = {part.x, part.y, part.z, part.w};
        #pragma unroll
        for (int q = 0; q < 4; ++q) {
          int r = r4 * 4 + q;
          int row_l = tile * 32 + q + 8 * r4 + 4 * half;
          lds_pack[row_l * 40 + col] = f2bf(fast_tanh(acc[r] + pv[q]));
        }
      }
    }
    __syncthreads();

    // ---- h store in A-fragment layout: one 16B store per thread ----
    {
      int tile_s = tid >> 7, kkl = (tid >> 6) & 1, flane = tid & 63;
      v8s hv = *(const v8s*)(lds_pack +
                             (tile_s * 32 + (flane & 31)) * 40 +
                             kkl * 16 + (flane >> 5) * 8);
      int slot_w = layer ? (BIGH2 ? t : (t & 1)) : (t + 1);
      unsigned short* hout = (layer ? h2buf : hbuf) +
          frag_off(slot_w, g, tile_s) + ((size_t)(2 * jt + kkl) * 64 + flane) * 8;
      store16_llc(hout, hv);
    }
    waitcnt_vm0();
    __syncthreads();
    if (tid == 0) {
      if (layer == 0) {
        __hip_atomic_fetch_add(cntA_g, 1u, __ATOMIC_RELAXED, __HIP_MEMORY_SCOPE_AGENT);
        __hip_atomic_fetch_add(cntX_g, 1u, __ATOMIC_RELAXED, __HIP_MEMORY_SCOPE_AGENT);
      } else {
        __hip_atomic_fetch_add(cntB_g, 1u, __ATOMIC_RELAXED, __HIP_MEMORY_SCOPE_AGENT);
      }
    }
  }
}

// fc over A-fragment h2last: h2f[g][tile][kk][lane][8]
__global__ __launch_bounds__(256, 1) void fc_kernel(
    const unsigned short* __restrict__ h2f, const float* __restrict__ fcW,
    const float* __restrict__ fcb, float* __restrict__ out) {
  const int tid = threadIdx.x;
  const int ct = blockIdx.x % 63;
  const int g = blockIdx.x / 63;
  const int lane = tid & 63;
  const int wave = tid >> 6;
  const int n = lane & 15;
  const int quad = lane >> 4;
  const int c = ct * 16 + n;
  const int cs = c < CC ? c : CC - 1;
  const float bias = fcb[cs];
  v4f acc = {bias, bias, bias, bias};
  const int brow = wave * 16 + n;
  const int tile = brow >> 5;
  const int flane = (brow & 31) + 32 * (quad & 1);
  const unsigned short* hb = h2f + (((size_t)g * 2 + tile) << 15) + (size_t)flane * 8;
  const float* wr = fcW + (size_t)cs * HH + quad * 8;
  #pragma unroll 8
  for (int kk = 0; kk < HH / 32; ++kk) {
    int c2 = kk * 2 + (quad >> 1);
    v8s a = *(const v8s*)(hb + (size_t)c2 * 512);
    float4 f0 = *(const float4*)(wr + kk * 32);
    float4 f1 = *(const float4*)(wr + kk * 32 + 4);
    v8s b;
    b[0] = (short)f2bf(f0.x); b[1] = (short)f2bf(f0.y);
    b[2] = (short)f2bf(f0.z); b[3] = (short)f2bf(f0.w);
    b[4] = (short)f2bf(f1.x); b[5] = (short)f2bf(f1.y);
    b[6] = (short)f2bf(f1.z); b[7] = (short)f2bf(f1.w);
    acc = __builtin_amdgcn_mfma_f32_16x16x32_bf16(a, b, acc, 0, 0, 0);
  }
  if (c < CC) {
    const int b0 = g * 64 + wave * 16 + quad * 4;
    #pragma unroll
    for (int i = 0; i < 4; ++i) out[(size_t)(b0 + i) * CC + c] = acc[i];
  }
}

extern "C" void kernel_launch(void* const* d_in, const int* in_sizes, int n_in,
                              void* d_out, int out_size, void* d_ws, size_t ws_size,
                              hipStream_t stream) {
  (void)in_sizes; (void)n_in; (void)out_size;
  const float* x    = (const float*)d_in[0];
  const float* Wih0 = (const float*)d_in[1];
  const float* Whh0 = (const float*)d_in[2];
  const float* bih0 = (const float*)d_in[3];
  const float* bhh0 = (const float*)d_in[4];
  const float* Wih1 = (const float*)d_in[5];
  const float* Whh1 = (const float*)d_in[6];
  const float* bih1 = (const float*)d_in[7];
  const float* bhh1 = (const float*)d_in[8];
  const float* fcW  = (const float*)d_in[9];
  const float* fcb  = (const float*)d_in[10];

  const size_t hbuf_elems = (size_t)(TT + 1) * BB * HH;
  const size_t h2_full = (size_t)TT * BB * HH;
  const size_t h2_par  = (size_t)2 * BB * HH;
  const size_t xp_elems = (size_t)TT * BB * HH;

  const size_t needA = (WSW_SHORTS + hbuf_elems + h2_full + xp_elems) * 2 + CNT_BYTES;
  const size_t needB = (WSW_SHORTS + hbuf_elems + h2_par + xp_elems) * 2 + CNT_BYTES;
  const bool tierA = ws_size >= needA;
  const bool tierB = !tierA && ws_size >= needB;

  unsigned short* wsw = (unsigned short*)d_ws;
  unsigned short* hbuf = wsw + WSW_SHORTS;
  unsigned short* h2buf = hbuf + hbuf_elems;
  unsigned short* xpbuf = h2buf + (tierA ? h2_full : h2_par);
  unsigned int* cnt = (unsigned int*)(xpbuf + ((tierA || tierB) ? xp_elems : 0));

  hipMemsetAsync(cnt, 0, CNT_BYTES, stream);
  swizzle_w<<<512, 256, 0, stream>>>(Whh0, wsw + OFF_WHH0, HH, 32 * 64 * 64);
  swizzle_w<<<512, 256, 0, stream>>>(Whh1, wsw + OFF_WHH1, HH, 32 * 64 * 64);
  swizzle_w<<<512, 256, 0, stream>>>(Wih1, wsw + OFF_WIH1, HH, 32 * 64 * 64);
  swizzle_w<<<128, 256, 0, stream>>>(Wih0, wsw + OFF_WIH0, II, 32 * 16 * 64);

  if (tierA || tierB)
    xp_kernel<<<1024, 256, 0, stream>>>(x, wsw + OFF_WIH0, bih0, bhh0, xpbuf);

  if (tierA) {
    rnn_fused<1, 1><<<256, 256, 0, stream>>>(
        x, wsw, xpbuf, bih0, bhh0, bih1, bhh1, hbuf, h2buf, cnt);
  } else if (tierB) {
    rnn_fused<1, 0><<<256, 256, 0, stream>>>(
        x, wsw, xpbuf, bih0, bhh0, bih1, bhh1, hbuf, h2buf, cnt);
  } else {
    rnn_fused<0, 0><<<256, 256, 0, stream>>>(
        x, wsw, xpbuf, bih0, bhh0, bih1, bhh1, hbuf, h2buf, cnt);
  }

  // h2 slot base for fc (A-fragment layout inside the slot)
  const unsigned short* h2last =
      h2buf + (size_t)(tierA ? (TT - 1) : 1) * BB * HH;
  fc_kernel<<<63 * 4, 256, 0, stream>>>(h2last, fcW, fcb, (float*)d_out);
}